// Round 4
// baseline (50.322 us; speedup 1.0000x reference)
//
#include <hip/hip_runtime.h>

constexpr int NPTS  = 1024;   // points per batch
constexpr int NT    = 21;     // targets per batch
constexpr int KSEL  = 64;     // top-k
constexpr int PPL   = 16;     // points per lane (1024 / 64)
constexpr int NXCD  = 8;

typedef float f32x4 __attribute__((ext_vector_type(4)));

__device__ __forceinline__ unsigned key_of(float d) {
    unsigned u = __float_as_uint(d);
    return (u & 0x80000000u) ? ~u : (u | 0x80000000u);
}

__device__ __forceinline__ unsigned mbcnt64(unsigned long long m) {
    unsigned lo = __builtin_amdgcn_mbcnt_lo((unsigned)m, 0u);
    return __builtin_amdgcn_mbcnt_hi((unsigned)(m >> 32), lo);
}

// Select phases shared by both paths: returns 16-bit selmask for this lane's
// 16 consecutive points of (b,tq). Bit-identical to the passing round-3 code.
__device__ __forceinline__ unsigned compute_selmask(
    const f32x4* __restrict__ src4, const float* __restrict__ tgt,
    int b, int tq, int lane)
{
    const float* tp = tgt + ((size_t)b * NT + tq) * 3;
    const float  t0 = tp[0], t1 = tp[1], t2 = tp[2];
    const float  dt = t0 * t0 + t1 * t1 + t2 * t2;

    unsigned key[PPL];
    {
        float f[PPL * 3];
        const f32x4* src = src4 + (size_t)lane * 12;
        #pragma unroll
        for (int j = 0; j < 12; ++j) {
            const f32x4 v = src[j];
            f[4 * j + 0] = v.x; f[4 * j + 1] = v.y;
            f[4 * j + 2] = v.z; f[4 * j + 3] = v.w;
        }
        #pragma unroll
        for (int i = 0; i < PPL; ++i) {
            const float p0 = f[3 * i + 0];
            const float p1 = f[3 * i + 1];
            const float p2 = f[3 * i + 2];
            const float d  = dt + (p0 * p0 + p1 * p1 + p2 * p2)
                                - 2.0f * (t0 * p0 + t1 * p1 + t2 * p2);
            key[i] = key_of(d);
        }
    }

    unsigned p = 0, want = KSEL, cls = NPTS;
    int s = 32;
    bool early = false;
    while (s > 0) {
        --s;
        const unsigned p2 = p << 1;
        unsigned cnt = 0;
        #pragma unroll
        for (int i = 0; i < PPL; ++i) cnt += ((key[i] >> s) == p2) ? 1u : 0u;
        unsigned total = 0;
        #pragma unroll
        for (int j = 0; j < 5; ++j)
            total += (unsigned)__popcll(__ballot((cnt >> j) & 1u)) << j;
        if (want <= total) { p = p2;        cls  = total; }
        else               { want -= total; p = p2 | 1u;  cls -= total; }
        if (cls == want) { early = true; break; }
    }

    unsigned selmask = 0;
    if (early) {
        #pragma unroll
        for (int i = 0; i < PPL; ++i)
            if ((key[i] >> s) <= p) selmask |= (1u << i);
    } else {
        const unsigned kth = p;
        unsigned cnt_eq = 0;
        #pragma unroll
        for (int i = 0; i < PPL; ++i) cnt_eq += (key[i] == kth) ? 1u : 0u;
        unsigned run = 0;
        #pragma unroll
        for (int j = 0; j < 5; ++j)
            run += mbcnt64(__ballot((cnt_eq >> j) & 1u)) << j;
        #pragma unroll
        for (int i = 0; i < PPL; ++i) {
            const bool eq = (key[i] == kth);
            if (key[i] < kth || (eq && run < want)) selmask |= (1u << i);
            run += eq ? 1u : 0u;
        }
    }
    return selmask;
}

// ---- kernel 1: select only. Writes 128 B mask per (b,t) into ws. ----
__global__ __launch_bounds__(256) void knn_select_kernel(
    const float* __restrict__ pc, const float* __restrict__ tgt,
    unsigned short* __restrict__ mask_out, int total_bt)
{
    const int wave = threadIdx.x >> 6;
    const int lane = threadIdx.x & 63;
    // XCD-aware swizzle: consecutive logical blocks (same b) on one XCD
    const int cpx  = gridDim.x / NXCD;
    const int sbid = (blockIdx.x % NXCD) * cpx + blockIdx.x / NXCD;
    const int bt   = sbid * 4 + wave;
    if (bt >= total_bt) return;
    const int b  = bt / NT;
    const int tq = bt % NT;

    const f32x4* src4 = reinterpret_cast<const f32x4*>(pc + (size_t)b * (NPTS * 3));
    const unsigned selmask = compute_selmask(src4, tgt, b, tq, lane);
    mask_out[(size_t)bt * 64 + lane] = (unsigned short)selmask;  // coalesced 2B/lane
}

// ---- kernel 2: pure streaming masked write. One block per bt. ----
__global__ __launch_bounds__(256) void masked_write_kernel(
    const float* __restrict__ pc, const unsigned* __restrict__ mask,
    float* __restrict__ out, int total_bt)
{
    const int cpx = gridDim.x / NXCD;
    const int bt  = (blockIdx.x % NXCD) * cpx + blockIdx.x / NXCD;
    if (bt >= total_bt) return;
    const int b   = bt / NT;
    const int tid = threadIdx.x;

    const f32x4*    src4 = reinterpret_cast<const f32x4*>(pc + (size_t)b * (NPTS * 3));
    f32x4*          dst4 = reinterpret_cast<f32x4*>(out + (size_t)bt * (NPTS * 3));
    const unsigned* mk   = mask + (size_t)bt * 32;   // point q -> bit (q&31) of word q>>5

    #pragma unroll
    for (int k = 0; k < 3; ++k) {
        const int      m  = tid + 256 * k;           // float4 chunk index, coalesced
        const f32x4    g  = src4[m];
        const unsigned e0 = 4u * (unsigned)m;
        const unsigned q  = e0 / 3u;
        const unsigned u  = e0 - 3u * q;
        const unsigned w0 = mk[q >> 5];
        const unsigned w1 = mk[(q + 1u) >> 5];
        const unsigned b0 = (w0 >> (q & 31u)) & 1u;
        const unsigned b1 = (w1 >> ((q + 1u) & 31u)) & 1u;
        f32x4 v;
        v.x = b0                    ? g.x : 0.0f;
        v.y = ((u == 2u) ? b1 : b0) ? g.y : 0.0f;
        v.z = ((u == 0u) ? b0 : b1) ? g.z : 0.0f;
        v.w = b1                    ? g.w : 0.0f;
        dst4[m] = v;
    }
}

// ---- fallback: round-3 fused kernel (used only if ws is too small) ----
__global__ __launch_bounds__(256) void knn_mask_fused_kernel(
    const float* __restrict__ pc, const float* __restrict__ tgt,
    float* __restrict__ out, int total_bt)
{
    const int wave = threadIdx.x >> 6;
    const int lane = threadIdx.x & 63;
    const int bt   = blockIdx.x * 4 + wave;
    if (bt >= total_bt) return;
    const int b  = bt / NT;
    const int tq = bt % NT;

    const f32x4* src4 = reinterpret_cast<const f32x4*>(pc + (size_t)b * (NPTS * 3));
    const unsigned selmask = compute_selmask(src4, tgt, b, tq, lane);

    f32x4* dst4 = reinterpret_cast<f32x4*>(out + (size_t)bt * (NPTS * 3));
    #pragma unroll
    for (int j = 0; j < 12; ++j) {
        const int      m  = 64 * j + lane;
        const f32x4    g  = src4[m];
        const unsigned e0 = 4u * (unsigned)m;
        const unsigned q  = e0 / 3u;
        const unsigned u  = e0 - 3u * q;
        const unsigned sm0 = (unsigned)__shfl((int)selmask, (int)(q >> 4), 64);
        const unsigned sm1 = (unsigned)__shfl((int)selmask, (int)((q + 1u) >> 4), 64);
        const unsigned b0  = (sm0 >> (q & 15u)) & 1u;
        const unsigned b1  = (sm1 >> ((q + 1u) & 15u)) & 1u;
        f32x4 v;
        v.x = b0                    ? g.x : 0.0f;
        v.y = ((u == 2u) ? b1 : b0) ? g.y : 0.0f;
        v.z = ((u == 0u) ? b0 : b1) ? g.z : 0.0f;
        v.w = b1                    ? g.w : 0.0f;
        dst4[m] = v;
    }
}

extern "C" void kernel_launch(void* const* d_in, const int* in_sizes, int n_in,
                              void* d_out, int out_size, void* d_ws, size_t ws_size,
                              hipStream_t stream) {
    const float* pc  = (const float*)d_in[0];  // (B,1024,3)
    const float* tgt = (const float*)d_in[1];  // (B,21,3)
    float*       out = (float*)d_out;          // (B,21,1024,3)

    const int B        = in_sizes[0] / (NPTS * 3);   // 512
    const int total_bt = B * NT;                      // 10752

    const size_t ws_needed = (size_t)total_bt * 128;  // 1.37 MB of masks
    if (ws_size >= ws_needed && d_ws != nullptr) {
        const int nb1 = (total_bt + 3) / 4;           // 2688 (divisible by 8)
        knn_select_kernel<<<nb1, 256, 0, stream>>>(
            pc, tgt, (unsigned short*)d_ws, total_bt);
        masked_write_kernel<<<total_bt, 256, 0, stream>>>(
            pc, (const unsigned*)d_ws, out, total_bt);
    } else {
        const int nb = (total_bt + 3) / 4;
        knn_mask_fused_kernel<<<nb, 256, 0, stream>>>(pc, tgt, out, total_bt);
    }
}

// Round 5
// 38.756 us; speedup vs baseline: 1.2984x; 1.2984x over previous
//
#include <hip/hip_runtime.h>

constexpr int NPTS  = 1024;   // points per batch
constexpr int NT    = 21;     // targets per batch
constexpr int KSEL  = 64;     // top-k
constexpr int BLOCK = 256;    // 4 waves, 1 wave per (b,t)
constexpr int PPL   = 16;     // points per lane (1024 / 64)
constexpr int NXCD  = 8;

typedef float f32x4 __attribute__((ext_vector_type(4)));

__device__ __forceinline__ unsigned key_of(float d) {
    // monotone float->uint transform (total order matching float <)
    unsigned u = __float_as_uint(d);
    return (u & 0x80000000u) ? ~u : (u | 0x80000000u);
}

__device__ __forceinline__ unsigned mbcnt64(unsigned long long m) {
    unsigned lo = __builtin_amdgcn_mbcnt_lo((unsigned)m, 0u);
    return __builtin_amdgcn_mbcnt_hi((unsigned)(m >> 32), lo);
}

__global__ __launch_bounds__(BLOCK) void knn_mask_fused_kernel(
    const float* __restrict__ pc,   // (B, 1024, 3)
    const float* __restrict__ tgt,  // (B, 21, 3)
    float* __restrict__ out,        // (B, 21, 1024, 3)
    int total_bt)
{
    const int wave = threadIdx.x >> 6;
    const int lane = threadIdx.x & 63;
    // bijective XCD swizzle (gridDim.x divisible by 8): consecutive logical
    // blocks (same b -> same pc tile) land on the same XCD's L2
    const int cpx  = gridDim.x / NXCD;
    const int sbid = ((int)blockIdx.x % NXCD) * cpx + (int)blockIdx.x / NXCD;
    const int bt   = sbid * 4 + wave;
    if (bt >= total_bt) return;          // wave-uniform
    const int b  = bt / NT;
    const int tq = bt % NT;

    const float* base = pc + (size_t)b * (NPTS * 3);

    // target point (wave-uniform, L1-broadcast)
    const float* tp = tgt + ((size_t)b * NT + tq) * 3;
    const float  t0 = tp[0], t1 = tp[1], t2 = tp[2];
    const float  dt = t0 * t0 + t1 * t1 + t2 * t2;

    // ---- phase 1: STRIDED ownership — lane owns points q_i = 64*i + lane.
    // float3 loads at lane-stride 12 B: each wave instr spans 768 contiguous
    // bytes (~13 lines) instead of 64 lines. Keys computed immediately.
    unsigned key[PPL];
    #pragma unroll
    for (int i = 0; i < PPL; ++i) {
        const float* pp = base + 3 * (64 * i + lane);
        const float p0 = pp[0];
        const float p1 = pp[1];
        const float p2 = pp[2];
        const float d  = dt + (p0 * p0 + p1 * p1 + p2 * p2)
                            - 2.0f * (t0 * p0 + t1 * p1 + t2 * p2);
        key[i] = key_of(d);
    }

    // ---- phase 2: barrier-free bitwise binary search for the KSEL-th smallest
    unsigned p = 0, want = KSEL, cls = NPTS;
    int s = 32;
    bool early = false;
    while (s > 0) {
        --s;
        const unsigned p2 = p << 1;      // candidate prefix with next bit = 0
        unsigned cnt = 0;
        #pragma unroll
        for (int i = 0; i < PPL; ++i) cnt += ((key[i] >> s) == p2) ? 1u : 0u;
        unsigned total = 0;
        #pragma unroll
        for (int j = 0; j < 5; ++j)
            total += (unsigned)__popcll(__ballot((cnt >> j) & 1u)) << j;
        if (want <= total) { p = p2;        cls  = total; }
        else               { want -= total; p = p2 | 1u;  cls -= total; }
        if (cls == want) { early = true; break; }   // whole candidate class selected
    }

    // ---- phase 3: selection flags. bit i of selmask => point (64*i + lane).
    // Stable lowest-INDEX tie-break; index = 64*i + lane, so order is
    // i-major then lane: accumulate equal-key counts i by i.
    unsigned selmask = 0;
    if (early) {
        #pragma unroll
        for (int i = 0; i < PPL; ++i)
            if ((key[i] >> s) <= p) selmask |= (1u << i);
    } else {
        const unsigned kth = p;          // exact key at sorted position KSEL-1
        unsigned run_tot = 0;            // equal keys with index < current group
        #pragma unroll
        for (int i = 0; i < PPL; ++i) {
            const bool eq = (key[i] == kth);
            const unsigned long long bal = __ballot(eq);
            const bool sel_eq = eq && (run_tot + mbcnt64(bal)) < want;
            if (key[i] < kth || sel_eq) selmask |= (1u << i);
            run_tot += (unsigned)__popcll(bal);
        }
    }

    // ---- phase 4: fully-coalesced store. lane stores float4 chunk m = 64j+lane;
    // point q selected <=> bit (q>>6) of lane (q&63)'s selmask (via bpermute).
    const f32x4* src4 = reinterpret_cast<const f32x4*>(base);
    f32x4*       dst4 = reinterpret_cast<f32x4*>(out + (size_t)bt * (NPTS * 3));
    #pragma unroll
    for (int j = 0; j < 12; ++j) {
        const int      m  = 64 * j + lane;
        const f32x4    g  = src4[m];
        const unsigned e0 = 4u * (unsigned)m;
        const unsigned q  = e0 / 3u;          // first point covered by this chunk
        const unsigned u  = e0 - 3u * q;      // 0..2: chunk-start offset in point q
        const unsigned sm0 = (unsigned)__shfl((int)selmask, (int)(q & 63u), 64);
        const unsigned sm1 = (unsigned)__shfl((int)selmask, (int)((q + 1u) & 63u), 64);
        const unsigned b0  = (sm0 >> (q >> 6)) & 1u;
        const unsigned b1  = (sm1 >> ((q + 1u) >> 6)) & 1u;
        f32x4 v;
        v.x = b0                    ? g.x : 0.0f;   // elem e0   -> point q
        v.y = ((u == 2u) ? b1 : b0) ? g.y : 0.0f;   // elem e0+1
        v.z = ((u == 0u) ? b0 : b1) ? g.z : 0.0f;   // elem e0+2
        v.w = b1                    ? g.w : 0.0f;   // elem e0+3 -> point q+1
        dst4[m] = v;
    }
}

extern "C" void kernel_launch(void* const* d_in, const int* in_sizes, int n_in,
                              void* d_out, int out_size, void* d_ws, size_t ws_size,
                              hipStream_t stream) {
    const float* pc  = (const float*)d_in[0];  // (B,1024,3)
    const float* tgt = (const float*)d_in[1];  // (B,21,3)
    float*       out = (float*)d_out;          // (B,21,1024,3)

    const int B        = in_sizes[0] / (NPTS * 3);   // 512
    const int total_bt = B * NT;                      // 10752
    const int nblocks  = (total_bt + 3) / 4;          // 2688 (divisible by 8)

    knn_mask_fused_kernel<<<nblocks, BLOCK, 0, stream>>>(pc, tgt, out, total_bt);
}

// Round 6
// 35.729 us; speedup vs baseline: 1.4084x; 1.0847x over previous
//
#include <hip/hip_runtime.h>

constexpr int NPTS  = 1024;   // points per batch
constexpr int NT    = 21;     // targets per batch
constexpr int KSEL  = 64;     // top-k
constexpr int BLOCK = 256;    // 4 waves, 1 wave per (b,t)
constexpr int PPL   = 16;     // points per lane (1024 / 64)
constexpr int NXCD  = 8;

typedef float f32x4 __attribute__((ext_vector_type(4)));

__device__ __forceinline__ unsigned key_of(float d) {
    // monotone float->uint transform (total order matching float <)
    unsigned u = __float_as_uint(d);
    return (u & 0x80000000u) ? ~u : (u | 0x80000000u);
}

__device__ __forceinline__ unsigned mbcnt64(unsigned long long m) {
    unsigned lo = __builtin_amdgcn_mbcnt_lo((unsigned)m, 0u);
    return __builtin_amdgcn_mbcnt_hi((unsigned)(m >> 32), lo);
}

__global__ __launch_bounds__(BLOCK) void knn_mask_fused_kernel(
    const float* __restrict__ pc,   // (B, 1024, 3)
    const float* __restrict__ tgt,  // (B, 21, 3)
    float* __restrict__ out,        // (B, 21, 1024, 3)
    int total_bt)
{
    const int wave = threadIdx.x >> 6;
    const int lane = threadIdx.x & 63;
    // bijective XCD swizzle (gridDim.x divisible by 8)
    const int cpx  = gridDim.x / NXCD;
    const int sbid = ((int)blockIdx.x % NXCD) * cpx + (int)blockIdx.x / NXCD;
    const int bt   = sbid * 4 + wave;
    if (bt >= total_bt) return;          // wave-uniform
    const int b  = bt / NT;
    const int tq = bt % NT;

    const float* base = pc  + (size_t)b  * (NPTS * 3);
    float*       obase = out + (size_t)bt * (NPTS * 3);

    // ---- phase 0: select-INDEPENDENT zeroing of the whole output row.
    // Issued immediately -> write pipe saturated while select computes.
    {
        f32x4* dst4 = reinterpret_cast<f32x4*>(obase);
        const f32x4 z = {0.0f, 0.0f, 0.0f, 0.0f};
        #pragma unroll
        for (int j = 0; j < 12; ++j) dst4[64 * j + lane] = z;
    }

    // target point (wave-uniform, L1-broadcast)
    const float* tp = tgt + ((size_t)b * NT + tq) * 3;
    const float  t0 = tp[0], t1 = tp[1], t2 = tp[2];
    const float  dt = t0 * t0 + t1 * t1 + t2 * t2;

    // ---- phase 1: strided ownership — lane owns points q_i = 64*i + lane ----
    unsigned key[PPL];
    #pragma unroll
    for (int i = 0; i < PPL; ++i) {
        const float* pp = base + 3 * (64 * i + lane);
        const float p0 = pp[0];
        const float p1 = pp[1];
        const float p2 = pp[2];
        const float d  = dt + (p0 * p0 + p1 * p1 + p2 * p2)
                            - 2.0f * (t0 * p0 + t1 * p1 + t2 * p2);
        key[i] = key_of(d);
    }

    // ---- phase 2: barrier-free bitwise binary search for the KSEL-th smallest
    unsigned p = 0, want = KSEL, cls = NPTS;
    int s = 32;
    bool early = false;
    while (s > 0) {
        --s;
        const unsigned p2 = p << 1;
        unsigned cnt = 0;
        #pragma unroll
        for (int i = 0; i < PPL; ++i) cnt += ((key[i] >> s) == p2) ? 1u : 0u;
        unsigned total = 0;
        #pragma unroll
        for (int j = 0; j < 5; ++j)
            total += (unsigned)__popcll(__ballot((cnt >> j) & 1u)) << j;
        if (want <= total) { p = p2;        cls  = total; }
        else               { want -= total; p = p2 | 1u;  cls -= total; }
        if (cls == want) { early = true; break; }
    }

    // ---- phase 3: selection flags. bit i => point (64*i + lane). ----
    unsigned selmask = 0;
    if (early) {
        #pragma unroll
        for (int i = 0; i < PPL; ++i)
            if ((key[i] >> s) <= p) selmask |= (1u << i);
    } else {
        const unsigned kth = p;
        unsigned run_tot = 0;   // stable lowest-index ties: index = 64*i + lane
        #pragma unroll
        for (int i = 0; i < PPL; ++i) {
            const bool eq = (key[i] == kth);
            const unsigned long long bal = __ballot(eq);
            const bool sel_eq = eq && (run_tot + mbcnt64(bal)) < want;
            if (key[i] < kth || sel_eq) selmask |= (1u << i);
            run_tot += (unsigned)__popcll(bal);
        }
    }

    // ---- phase 4: store ONLY the selected points (avg 1 per lane, 12 B each).
    // The zero-stores were issued ~1500+ cycles ago and have retired; the
    // explicit vmcnt(0) guarantees same-address ordering (ISA gives none) and
    // costs ~nothing. Lines are still dirty in this XCD's L2 -> value stores
    // merge in L2; HBM write traffic stays ~129 MB.
    asm volatile("s_waitcnt vmcnt(0)" ::: "memory");
    unsigned sm = selmask;
    while (sm) {
        const int i = __builtin_ctz(sm);
        sm &= sm - 1u;
        const int q = 64 * i + lane;
        const float* pp = base  + 3 * q;   // L1-hot (read in phase 1)
        float*       op = obase + 3 * q;
        op[0] = pp[0];
        op[1] = pp[1];
        op[2] = pp[2];
    }
}

extern "C" void kernel_launch(void* const* d_in, const int* in_sizes, int n_in,
                              void* d_out, int out_size, void* d_ws, size_t ws_size,
                              hipStream_t stream) {
    const float* pc  = (const float*)d_in[0];  // (B,1024,3)
    const float* tgt = (const float*)d_in[1];  // (B,21,3)
    float*       out = (float*)d_out;          // (B,21,1024,3)

    const int B        = in_sizes[0] / (NPTS * 3);   // 512
    const int total_bt = B * NT;                      // 10752
    const int nblocks  = (total_bt + 3) / 4;          // 2688 (divisible by 8)

    knn_mask_fused_kernel<<<nblocks, BLOCK, 0, stream>>>(pc, tgt, out, total_bt);
}